// Round 6
// baseline (83.707 us; speedup 1.0000x reference)
//
#include <hip/hip_runtime.h>

#define H_OUT 8
#define W_OUT 8
#define MAXG 4
#define CCHUNK 8   // channels per block
#define RSLOTS 6   // max distinct feature rows per output bin (<=5, padded)

// Separable ROI-align with row-collapsed weights: rois[c] = Wy * F[c] * Wx^T.
// Block = (box n, channel-chunk of 8), 256 threads.
//  Build: per-axis per-bin collapsed row weights (<=5 rows/bin) by 16 threads.
//  Stage A: tmp[c][py][x] = sum_j w_y[py][j] * F[c][rbase_y[py]+j][x]
//           (float4 coalesced global loads, 2 channels/thread)
//  Stage B: out[c][py][px] = sum_j w_x[px][j] * tmp[c][py][xbase+j] (LDS)
__global__ __launch_bounds__(256) void ordered_roi_kernel(
    const float* __restrict__ feats,        // [B,C,32,32]
    const int*   __restrict__ batch_idxs,   // [N]
    const int*   __restrict__ starts,       // [N,2]
    const int*   __restrict__ goals,        // [N,2]
    float*       __restrict__ out,          // [N,C,8,8]
    int C, int CG)                          // CG = C / CCHUNK
{
    const int bx  = blockIdx.x;
    const int n   = bx / CG;
    const int cg  = bx - n * CG;
    const int tid = threadIdx.x;

    // ---- per-box params (wave-uniform) ----
    const float s0 = (float)starts[2 * n + 0];
    const float s1 = (float)starts[2 * n + 1];
    const float g0 = (float)goals[2 * n + 0];
    const float g1 = (float)goals[2 * n + 1];
    const float y_min = fminf(s0, g0), y_max = fmaxf(s0, g0);
    const float x_min = fminf(s1, g1), x_max = fmaxf(s1, g1);
    const bool  y_rev = s0 > g0;
    const bool  x_rev = s1 > g1;
    const float start_h = y_min - 0.5f;
    const float start_w = x_min - 0.5f;
    const float bin_h = (y_max - y_min) / (float)H_OUT;
    const float bin_w = (x_max - x_min) / (float)W_OUT;
    const int   gh = (int)ceilf(bin_h);
    const int   gw = (int)ceilf(bin_w);
    const float inv_count = 1.0f / fmaxf((float)(gh * gw), 1.0f);

    // ---- row-collapsed per-axis tables ----
    __shared__ int   s_rbase[2][H_OUT];
    __shared__ int   s_rcnt[2][H_OUT];
    __shared__ float s_rw[2][H_OUT][RSLOTS];
    __shared__ float s_t[CCHUNK][H_OUT][33];   // pitch 33: stage-B bank spread

    if (tid < 16) {
        const int axis = tid >> 3;      // 0 = y, 1 = x
        const int ph   = tid & 7;
        const float start = axis ? start_w : start_h;
        const float bin   = axis ? bin_w  : bin_h;
        const int   grid  = axis ? gw     : gh;
        const float gsafe = (float)(grid > 1 ? grid : 1);
        float wloc[RSLOTS] = {0.f, 0.f, 0.f, 0.f, 0.f, 0.f};
        int base = 0, last = -1;
        for (int i = 0; i < grid && i < MAXG; ++i) {
            const float pos = start + (float)ph * bin + ((float)i + 0.5f) * (bin / gsafe);
            const float vf  = (pos >= -1.0f && pos <= 32.0f) ? 1.0f : 0.0f;
            const float p   = fminf(fmaxf(pos, 0.0f), 31.0f);
            const int   lo  = (int)floorf(p);
            const int   hi  = min(lo + 1, 31);
            const float l   = p - (float)lo;
            if (i == 0) base = lo;
            wloc[lo - base] += (1.0f - l) * vf;   // pos monotone in i -> lo >= base
            wloc[hi - base] += l * vf;
            last = hi;
        }
        s_rbase[axis][ph] = base;
        s_rcnt[axis][ph]  = (grid > 0) ? (last - base + 1) : 0;
        #pragma unroll
        for (int k = 0; k < RSLOTS; ++k) s_rw[axis][ph][k] = wloc[k];
    }
    __syncthreads();

    // ================= Stage A: y-reduction (float4 loads) =================
    // tid = cp*64 + py*8 + xq ; channels {cp, cp+4}, x-quad of 4
    {
        const int cp = tid >> 6;          // 0..3
        const int py = (tid >> 3) & 7;
        const int xq = tid & 7;
        const int rb = s_rbase[0][py];
        const int rc = s_rcnt[0][py];

        const int b = batch_idxs[n];
        const float* __restrict__ fb =
            feats + ((size_t)b * C + (size_t)cg * CCHUNK) * 1024;
        const float* __restrict__ fc0 = fb + (size_t)cp * 1024 + xq * 4;
        const float* __restrict__ fc1 = fc0 + 4 * 1024;

        float a00 = 0.f, a01 = 0.f, a02 = 0.f, a03 = 0.f;
        float a10 = 0.f, a11 = 0.f, a12 = 0.f, a13 = 0.f;
        for (int j = 0; j < rc; ++j) {
            const float w = s_rw[0][py][j];
            const float4 r0 = *reinterpret_cast<const float4*>(fc0 + (rb + j) * 32);
            const float4 r1 = *reinterpret_cast<const float4*>(fc1 + (rb + j) * 32);
            a00 = fmaf(w, r0.x, a00); a01 = fmaf(w, r0.y, a01);
            a02 = fmaf(w, r0.z, a02); a03 = fmaf(w, r0.w, a03);
            a10 = fmaf(w, r1.x, a10); a11 = fmaf(w, r1.y, a11);
            a12 = fmaf(w, r1.z, a12); a13 = fmaf(w, r1.w, a13);
        }
        const int x0 = xq * 4;
        s_t[cp][py][x0 + 0] = a00; s_t[cp][py][x0 + 1] = a01;
        s_t[cp][py][x0 + 2] = a02; s_t[cp][py][x0 + 3] = a03;
        s_t[cp + 4][py][x0 + 0] = a10; s_t[cp + 4][py][x0 + 1] = a11;
        s_t[cp + 4][py][x0 + 2] = a12; s_t[cp + 4][py][x0 + 3] = a13;
    }
    __syncthreads();

    // ================= Stage B: x-reduction + flip + write =================
    // outputs o = {tid, tid+256}; o -> (c = o>>6, y = (o>>3)&7, x = o&7)
    const int yx = tid & 63;
    const int y  = yx >> 3;
    const int xo = yx & 7;
    const int c0 = tid >> 6;   // 0..3 ; second output uses c0+4

    // flip-gather source bin (faithful reference-table quirk):
    //  none: (y,x) ; x_rev XOR y_rev: (y, 7-y) ; both: (7-y, x)
    int py, px;
    if (y_rev && x_rev)      { py = H_OUT - 1 - y; px = xo; }
    else if (y_rev || x_rev) { py = y;             px = W_OUT - 1 - y; }
    else                     { py = y;             px = xo; }

    const int xb = s_rbase[1][px];
    const int xc = s_rcnt[1][px];
    float acc0 = 0.0f, acc1 = 0.0f;
    for (int j = 0; j < xc; ++j) {
        const float w = s_rw[1][px][j];
        acc0 = fmaf(w, s_t[c0][py][xb + j],     acc0);
        acc1 = fmaf(w, s_t[c0 + 4][py][xb + j], acc1);
    }

    float* __restrict__ ob =
        out + ((size_t)n * C + (size_t)cg * CCHUNK) * (H_OUT * W_OUT);
    ob[tid]       = acc0 * inv_count;
    ob[tid + 256] = acc1 * inv_count;
}

extern "C" void kernel_launch(void* const* d_in, const int* in_sizes, int n_in,
                              void* d_out, int out_size, void* d_ws, size_t ws_size,
                              hipStream_t stream) {
    const float* feats      = (const float*)d_in[0];
    const int*   batch_idxs = (const int*)d_in[1];
    const int*   starts     = (const int*)d_in[2];
    const int*   goals      = (const int*)d_in[3];
    float*       out        = (float*)d_out;

    const int N  = in_sizes[1];                       // 1024
    const int C  = out_size / (N * H_OUT * W_OUT);    // 64
    const int CG = C / CCHUNK;                        // 8

    ordered_roi_kernel<<<N * CG, 256, 0, stream>>>(feats, batch_idxs, starts, goals,
                                                   out, C, CG);
}

// Round 8
// 78.742 us; speedup vs baseline: 1.0631x; 1.0631x over previous
//
#include <hip/hip_runtime.h>

#define H_OUT 8
#define W_OUT 8
#define MAXG 4
#define CCHUNK 16    // channels per block (kernel 2)
#define RSLOTS 6     // max distinct feature rows per bin (<=5, padded)
#define TSTRIDE 160  // floats per box in the ws table

// ---------------- kernel 1: per-box separable tables -> d_ws ----------------
// thread t -> (box n = t>>4, slot = t&15, axis = slot>>3, bin ph = slot&7)
// Layout per box (floats, stride TSTRIDE):
//   [0..47]    rw_y[8][6]   collapsed row weights, y axis
//   [48..95]   rw_x[8][6]
//   [96..103]  rbase_y[8]   (as float)   [104..111] rcnt_y[8]
//   [112..119] rbase_x[8]                [120..127] rcnt_x[8]
//   [128] inv_count   [129] flip code (y_rev*2+x_rev)   [130] batch idx
__global__ __launch_bounds__(256) void build_tables(
    const int* __restrict__ batch_idxs,
    const int* __restrict__ starts,
    const int* __restrict__ goals,
    float*     __restrict__ tab, int N)
{
    const int t = blockIdx.x * 256 + threadIdx.x;
    if (t >= N * 16) return;
    const int n    = t >> 4;
    const int slot = t & 15;
    const int axis = slot >> 3;     // 0 = y, 1 = x
    const int ph   = slot & 7;

    const float s0 = (float)starts[2 * n + 0];
    const float s1 = (float)starts[2 * n + 1];
    const float g0 = (float)goals[2 * n + 0];
    const float g1 = (float)goals[2 * n + 1];
    const float y_min = fminf(s0, g0), y_max = fmaxf(s0, g0);
    const float x_min = fminf(s1, g1), x_max = fmaxf(s1, g1);
    const float bin_h = (y_max - y_min) * 0.125f;
    const float bin_w = (x_max - x_min) * 0.125f;
    const int   gh = (int)ceilf(bin_h);
    const int   gw = (int)ceilf(bin_w);

    const float start = axis ? (x_min - 0.5f) : (y_min - 0.5f);
    const float bin   = axis ? bin_w : bin_h;
    const int   grid  = axis ? gw : gh;          // <= MAXG
    const float gsafe = (float)(grid > 1 ? grid : 1);

    float wloc[RSLOTS] = {0.f, 0.f, 0.f, 0.f, 0.f, 0.f};
    int base = 0, last = -1;
    for (int i = 0; i < grid; ++i) {
        const float pos = start + (float)ph * bin + ((float)i + 0.5f) * (bin / gsafe);
        const float vf  = (pos >= -1.0f && pos <= 32.0f) ? 1.0f : 0.0f;
        const float p   = fminf(fmaxf(pos, 0.0f), 31.0f);
        const int   lo  = (int)floorf(p);
        const int   hi  = min(lo + 1, 31);
        const float l   = p - (float)lo;
        if (i == 0) base = lo;
        wloc[lo - base] += (1.0f - l) * vf;   // pos monotone in i -> lo >= base
        wloc[hi - base] += l * vf;            // hi-base <= 4+1 < RSLOTS
        last = hi;
    }

    float* __restrict__ tb = tab + (size_t)n * TSTRIDE;
    #pragma unroll
    for (int k = 0; k < RSLOTS; ++k) tb[axis * 48 + ph * 6 + k] = wloc[k];
    tb[96  + axis * 16 + ph] = (float)base;
    tb[104 + axis * 16 + ph] = (float)((grid > 0) ? (last - base + 1) : 0);
    if (slot == 0) {
        const bool y_rev = s0 > g0;
        const bool x_rev = s1 > g1;
        tb[128] = 1.0f / fmaxf((float)(gh * gw), 1.0f);
        tb[129] = (float)((y_rev ? 2 : 0) + (x_rev ? 1 : 0));
        tb[130] = (float)batch_idxs[n];
    }
}

// ---------------- kernel 2: separable ROI-align, one barrier ----------------
// Block = (box n, 16-channel chunk cg). 256 threads.
//  Stage A: tid = cp*64+py*8+xq; channels cp*4+k; float4 row loads, y-reduce,
//           float4 LDS writes (pitch 36 keeps 16B alignment).
//  Stage B: 4 outputs/thread at {tid+256k}; x-reduce from LDS + flip + write.
__global__ __launch_bounds__(256) void roi_main(
    const float* __restrict__ feats,   // [B,C,32,32]
    const float* __restrict__ tab,     // per-box tables
    float*       __restrict__ out,     // [N,C,8,8]
    int C, int CG)
{
    const int bx  = blockIdx.x;
    const int n   = bx / CG;
    const int cg  = bx - n * CG;
    const int tid = threadIdx.x;

    const float* __restrict__ tb = tab + (size_t)n * TSTRIDE;

    __shared__ float s_t[CCHUNK][H_OUT][36];

    // ================= Stage A: y-reduction =================
    {
        const int cp = tid >> 6;          // 0..3
        const int py = (tid >> 3) & 7;
        const int xq = tid & 7;
        const int rb = (int)tb[96 + py];
        const int rc = (int)tb[104 + py];
        const int b  = (int)tb[130];

        const float* __restrict__ fb =
            feats + ((size_t)b * C + (size_t)(cg * CCHUNK + cp * 4)) * 1024 + xq * 4;

        float4 a0 = {0.f,0.f,0.f,0.f}, a1 = {0.f,0.f,0.f,0.f};
        float4 a2 = {0.f,0.f,0.f,0.f}, a3 = {0.f,0.f,0.f,0.f};
        for (int j = 0; j < rc; ++j) {
            const float w  = tb[py * 6 + j];
            const int   ro = (rb + j) * 32;
            const float4 r0 = *reinterpret_cast<const float4*>(fb + ro);
            const float4 r1 = *reinterpret_cast<const float4*>(fb + 1024 + ro);
            const float4 r2 = *reinterpret_cast<const float4*>(fb + 2048 + ro);
            const float4 r3 = *reinterpret_cast<const float4*>(fb + 3072 + ro);
            a0.x = fmaf(w, r0.x, a0.x); a0.y = fmaf(w, r0.y, a0.y);
            a0.z = fmaf(w, r0.z, a0.z); a0.w = fmaf(w, r0.w, a0.w);
            a1.x = fmaf(w, r1.x, a1.x); a1.y = fmaf(w, r1.y, a1.y);
            a1.z = fmaf(w, r1.z, a1.z); a1.w = fmaf(w, r1.w, a1.w);
            a2.x = fmaf(w, r2.x, a2.x); a2.y = fmaf(w, r2.y, a2.y);
            a2.z = fmaf(w, r2.z, a2.z); a2.w = fmaf(w, r2.w, a2.w);
            a3.x = fmaf(w, r3.x, a3.x); a3.y = fmaf(w, r3.y, a3.y);
            a3.z = fmaf(w, r3.z, a3.z); a3.w = fmaf(w, r3.w, a3.w);
        }
        const int x0 = xq * 4;
        *reinterpret_cast<float4*>(&s_t[cp * 4 + 0][py][x0]) = a0;
        *reinterpret_cast<float4*>(&s_t[cp * 4 + 1][py][x0]) = a1;
        *reinterpret_cast<float4*>(&s_t[cp * 4 + 2][py][x0]) = a2;
        *reinterpret_cast<float4*>(&s_t[cp * 4 + 3][py][x0]) = a3;
    }
    __syncthreads();

    // ================= Stage B: x-reduction + flip + write =================
    const int yx = tid & 63;
    const int y  = yx >> 3;
    const int xo = yx & 7;
    const int c0 = tid >> 6;   // channels {c0, c0+4, c0+8, c0+12}

    // flip-gather source bin (faithful reference-table quirk):
    //  code 0: (y,x) ; codes 1,2 (xor): (y, 7-y) ; code 3: (7-y, x)
    const int fc = (int)tb[129];
    int py, px;
    if (fc == 3)      { py = H_OUT - 1 - y; px = xo; }
    else if (fc != 0) { py = y;             px = W_OUT - 1 - y; }
    else              { py = y;             px = xo; }

    const int   xb = (int)tb[112 + px];
    const int   xc = (int)tb[120 + px];
    const float inv_count = tb[128];

    float b0 = 0.f, b1 = 0.f, b2 = 0.f, b3 = 0.f;
    for (int j = 0; j < xc; ++j) {
        const float w = tb[48 + px * 6 + j];
        b0 = fmaf(w, s_t[c0     ][py][xb + j], b0);
        b1 = fmaf(w, s_t[c0 +  4][py][xb + j], b1);
        b2 = fmaf(w, s_t[c0 +  8][py][xb + j], b2);
        b3 = fmaf(w, s_t[c0 + 12][py][xb + j], b3);
    }

    float* __restrict__ ob =
        out + ((size_t)n * C + (size_t)cg * CCHUNK) * (H_OUT * W_OUT);
    ob[tid      ] = b0 * inv_count;
    ob[tid + 256] = b1 * inv_count;
    ob[tid + 512] = b2 * inv_count;
    ob[tid + 768] = b3 * inv_count;
}

extern "C" void kernel_launch(void* const* d_in, const int* in_sizes, int n_in,
                              void* d_out, int out_size, void* d_ws, size_t ws_size,
                              hipStream_t stream) {
    const float* feats      = (const float*)d_in[0];
    const int*   batch_idxs = (const int*)d_in[1];
    const int*   starts     = (const int*)d_in[2];
    const int*   goals      = (const int*)d_in[3];
    float*       out        = (float*)d_out;
    float*       tab        = (float*)d_ws;

    const int N  = in_sizes[1];                       // 1024
    const int C  = out_size / (N * H_OUT * W_OUT);    // 64
    const int CG = C / CCHUNK;                        // 4

    const int tb_blocks = (N * 16 + 255) / 256;       // 64
    build_tables<<<tb_blocks, 256, 0, stream>>>(batch_idxs, starts, goals, tab, N);
    roi_main<<<N * CG, 256, 0, stream>>>(feats, tab, out, C, CG);
}

// Round 10
// 76.633 us; speedup vs baseline: 1.0923x; 1.0275x over previous
//
#include <hip/hip_runtime.h>

#define H_OUT 8
#define W_OUT 8
#define MAXG 4
#define CCHUNK 16    // channels per block (kernel 2)
#define RSLOTS 6     // weight slots per bin record (max used = 5)
#define TSTRIDE 160  // floats per box in the ws table (16B aligned)

// ---------------- kernel 1: per-box separable tables -> d_ws ----------------
// Layout per box (floats, stride TSTRIDE):
//   [0..63]    yrec[8][8]  = {w0..w5, rbase, rcnt} per y-bin
//   [64..127]  xrec[8][8]  = {w0..w5, rbase, rcnt} per x-bin
//   [128..131] meta        = {inv_count, flip_code, batch, 0}
__global__ __launch_bounds__(256) void build_tables(
    const int* __restrict__ batch_idxs,
    const int* __restrict__ starts,
    const int* __restrict__ goals,
    float*     __restrict__ tab, int N)
{
    const int t = blockIdx.x * 256 + threadIdx.x;
    if (t >= N * 16) return;
    const int n    = t >> 4;
    const int slot = t & 15;
    const int axis = slot >> 3;     // 0 = y, 1 = x
    const int ph   = slot & 7;

    const float s0 = (float)starts[2 * n + 0];
    const float s1 = (float)starts[2 * n + 1];
    const float g0 = (float)goals[2 * n + 0];
    const float g1 = (float)goals[2 * n + 1];
    const float y_min = fminf(s0, g0), y_max = fmaxf(s0, g0);
    const float x_min = fminf(s1, g1), x_max = fmaxf(s1, g1);
    const float bin_h = (y_max - y_min) * 0.125f;
    const float bin_w = (x_max - x_min) * 0.125f;
    const int   gh = (int)ceilf(bin_h);
    const int   gw = (int)ceilf(bin_w);

    const float start = axis ? (x_min - 0.5f) : (y_min - 0.5f);
    const float bin   = axis ? bin_w : bin_h;
    const int   grid  = axis ? gw : gh;          // <= MAXG
    const float gsafe = (float)(grid > 1 ? grid : 1);

    float wloc[RSLOTS] = {0.f, 0.f, 0.f, 0.f, 0.f, 0.f};
    int base = 0, last = -1;
    for (int i = 0; i < grid; ++i) {
        const float pos = start + (float)ph * bin + ((float)i + 0.5f) * (bin / gsafe);
        const float vf  = (pos >= -1.0f && pos <= 32.0f) ? 1.0f : 0.0f;
        const float p   = fminf(fmaxf(pos, 0.0f), 31.0f);
        const int   lo  = (int)floorf(p);
        const int   hi  = min(lo + 1, 31);
        const float l   = p - (float)lo;
        if (i == 0) base = lo;
        wloc[lo - base] += (1.0f - l) * vf;   // pos monotone in i -> lo >= base
        wloc[hi - base] += l * vf;            // span <= 5 slots
        last = hi;
    }

    float* __restrict__ rec = tab + (size_t)n * TSTRIDE + axis * 64 + ph * 8;
    #pragma unroll
    for (int k = 0; k < RSLOTS; ++k) rec[k] = wloc[k];
    rec[6] = (float)base;
    rec[7] = (float)((grid > 0) ? (last - base + 1) : 0);
    if (slot == 0) {
        float* __restrict__ tb = tab + (size_t)n * TSTRIDE;
        const bool y_rev = s0 > g0;
        const bool x_rev = s1 > g1;
        tb[128] = 1.0f / fmaxf((float)(gh * gw), 1.0f);
        tb[129] = (float)((y_rev ? 2 : 0) + (x_rev ? 1 : 0));
        tb[130] = (float)batch_idxs[n];
        tb[131] = 0.0f;
    }
}

// ---------------- kernel 2: separable ROI-align, one barrier ----------------
// Block = (box n, 16-channel chunk cg). 256 threads.
//  Stage A: tid = py*32 + cp*8 + xq (wave spans 2 py bins); 3 float4 table
//           loads issued at entry; float4 row loads; float4 LDS writes.
//  Stage B: x-record float4 loads issued BEFORE the barrier; 4 outputs/thread.
__global__ __launch_bounds__(256) void roi_main(
    const float* __restrict__ feats,   // [B,C,32,32]
    const float* __restrict__ tab,     // per-box tables
    float*       __restrict__ out,     // [N,C,8,8]
    int C, int CG)
{
    const int bx  = blockIdx.x;
    const int n   = bx / CG;
    const int cg  = bx - n * CG;
    const int tid = threadIdx.x;

    const float* __restrict__ tb = tab + (size_t)n * TSTRIDE;

    __shared__ float s_t[CCHUNK][H_OUT][36];   // pitch 36: 16B-aligned, bank spread

    // ---- issue all stage-A table loads up front (independent float4s) ----
    const int py = tid >> 5;          // wave-uniform pairs
    const int cp = (tid >> 3) & 3;
    const int xq = tid & 7;
    const float4 ya   = *reinterpret_cast<const float4*>(tb + py * 8);
    const float4 yb   = *reinterpret_cast<const float4*>(tb + py * 8 + 4);
    const float4 meta = *reinterpret_cast<const float4*>(tb + 128);

    // ================= Stage A: y-reduction =================
    {
        const int rb = (int)yb.z;
        const int rc = (int)yb.w;
        const int b  = (int)meta.z;
        const float wy[6] = {ya.x, ya.y, ya.z, ya.w, yb.x, yb.y};

        const float* __restrict__ fb =
            feats + ((size_t)b * C + (size_t)(cg * CCHUNK + cp * 4)) * 1024 + xq * 4;

        float4 a0 = {0.f,0.f,0.f,0.f}, a1 = {0.f,0.f,0.f,0.f};
        float4 a2 = {0.f,0.f,0.f,0.f}, a3 = {0.f,0.f,0.f,0.f};
        #pragma unroll
        for (int j = 0; j < 5; ++j) {           // rc <= 5; compile-time wy index
            if (j < rc) {
                const float w  = wy[j];
                const int   ro = (rb + j) * 32;
                const float4 r0 = *reinterpret_cast<const float4*>(fb + ro);
                const float4 r1 = *reinterpret_cast<const float4*>(fb + 1024 + ro);
                const float4 r2 = *reinterpret_cast<const float4*>(fb + 2048 + ro);
                const float4 r3 = *reinterpret_cast<const float4*>(fb + 3072 + ro);
                a0.x = fmaf(w, r0.x, a0.x); a0.y = fmaf(w, r0.y, a0.y);
                a0.z = fmaf(w, r0.z, a0.z); a0.w = fmaf(w, r0.w, a0.w);
                a1.x = fmaf(w, r1.x, a1.x); a1.y = fmaf(w, r1.y, a1.y);
                a1.z = fmaf(w, r1.z, a1.z); a1.w = fmaf(w, r1.w, a1.w);
                a2.x = fmaf(w, r2.x, a2.x); a2.y = fmaf(w, r2.y, a2.y);
                a2.z = fmaf(w, r2.z, a2.z); a2.w = fmaf(w, r2.w, a2.w);
                a3.x = fmaf(w, r3.x, a3.x); a3.y = fmaf(w, r3.y, a3.y);
                a3.z = fmaf(w, r3.z, a3.z); a3.w = fmaf(w, r3.w, a3.w);
            }
        }
        const int x0 = xq * 4;
        *reinterpret_cast<float4*>(&s_t[cp * 4 + 0][py][x0]) = a0;
        *reinterpret_cast<float4*>(&s_t[cp * 4 + 1][py][x0]) = a1;
        *reinterpret_cast<float4*>(&s_t[cp * 4 + 2][py][x0]) = a2;
        *reinterpret_cast<float4*>(&s_t[cp * 4 + 3][py][x0]) = a3;
    }

    // ---- stage-B indices + x-record loads issued BEFORE the barrier ----
    const int yx = tid & 63;
    const int y  = yx >> 3;
    const int xo = yx & 7;
    const int c0 = tid >> 6;   // channels {c0, c0+4, c0+8, c0+12}

    // flip-gather source bin (faithful reference-table quirk):
    //  code 0: (y,x) ; codes 1,2 (xor): (y, 7-y) ; code 3: (7-y, x)
    const int fc = (int)meta.y;
    int py2, px;
    if (fc == 3)      { py2 = H_OUT - 1 - y; px = xo; }
    else if (fc != 0) { py2 = y;             px = W_OUT - 1 - y; }
    else              { py2 = y;             px = xo; }

    const float4 xa  = *reinterpret_cast<const float4*>(tb + 64 + px * 8);
    const float4 xb4 = *reinterpret_cast<const float4*>(tb + 64 + px * 8 + 4);

    __syncthreads();

    // ================= Stage B: x-reduction + flip + write =================
    const int   xbi = (int)xb4.z;
    const int   xc  = (int)xb4.w;
    const float wx[6] = {xa.x, xa.y, xa.z, xa.w, xb4.x, xb4.y};
    const float inv_count = meta.x;

    float b0 = 0.f, b1 = 0.f, b2 = 0.f, b3 = 0.f;
    #pragma unroll
    for (int j = 0; j < 5; ++j) {               // xc <= 5; compile-time wx index
        if (j < xc) {
            const float w = wx[j];
            b0 = fmaf(w, s_t[c0     ][py2][xbi + j], b0);
            b1 = fmaf(w, s_t[c0 +  4][py2][xbi + j], b1);
            b2 = fmaf(w, s_t[c0 +  8][py2][xbi + j], b2);
            b3 = fmaf(w, s_t[c0 + 12][py2][xbi + j], b3);
        }
    }

    float* __restrict__ ob =
        out + ((size_t)n * C + (size_t)cg * CCHUNK) * (H_OUT * W_OUT);
    ob[tid      ] = b0 * inv_count;
    ob[tid + 256] = b1 * inv_count;
    ob[tid + 512] = b2 * inv_count;
    ob[tid + 768] = b3 * inv_count;
}

extern "C" void kernel_launch(void* const* d_in, const int* in_sizes, int n_in,
                              void* d_out, int out_size, void* d_ws, size_t ws_size,
                              hipStream_t stream) {
    const float* feats      = (const float*)d_in[0];
    const int*   batch_idxs = (const int*)d_in[1];
    const int*   starts     = (const int*)d_in[2];
    const int*   goals      = (const int*)d_in[3];
    float*       out        = (float*)d_out;
    float*       tab        = (float*)d_ws;

    const int N  = in_sizes[1];                       // 1024
    const int C  = out_size / (N * H_OUT * W_OUT);    // 64
    const int CG = C / CCHUNK;                        // 4

    const int tb_blocks = (N * 16 + 255) / 256;       // 64
    build_tables<<<tb_blocks, 256, 0, stream>>>(batch_idxs, starts, goals, tab, N);
    roi_main<<<N * CG, 256, 0, stream>>>(feats, tab, out, C, CG);
}

// Round 11
// 73.252 us; speedup vs baseline: 1.1427x; 1.0461x over previous
//
#include <hip/hip_runtime.h>

#define H_OUT 8
#define W_OUT 8
#define CCHUNK 16    // channels per block

// Fused separable ROI-align + flip. One kernel, grid = N * (C/CCHUNK).
//  Phase 0 (threads 0..15): build per-box per-bin collapsed records into LDS
//     s_rec[axis][bin] = {w0..w4, pad, rbase, rcnt}  (runtime scatter -> LDS, no scratch)
//  Stage A (tid = py*32+cp*8+xq): y-reduction, float4 feats row loads, -> s_t
//  Stage B: x-record LDS loads issued BEFORE barrier; x-reduce + flip + write.
__global__ __launch_bounds__(256) void roi_fused(
    const float* __restrict__ feats,        // [B,C,32,32]
    const int*   __restrict__ batch_idxs,   // [N]
    const int*   __restrict__ starts,       // [N,2]
    const int*   __restrict__ goals,        // [N,2]
    float*       __restrict__ out,          // [N,C,8,8]
    int C, int CG)
{
    const int bx  = blockIdx.x;
    const int n   = bx / CG;
    const int cg  = bx - n * CG;
    const int tid = threadIdx.x;

    __shared__ float s_rec[2][8][8];          // [axis][bin][w0..w4,pad,rb,rc]
    __shared__ float s_meta[4];               // {inv_count, flip_code, batch, -}
    __shared__ float s_t[CCHUNK][H_OUT][36];  // pitch 36: 16B-aligned, bank spread

    // ---------------- Phase 0: in-block table build (16 threads) ----------------
    if (tid < 16) {
        const int axis = tid >> 3;      // 0 = y, 1 = x
        const int ph   = tid & 7;
        const float s0 = (float)starts[2 * n + 0];
        const float s1 = (float)starts[2 * n + 1];
        const float g0 = (float)goals[2 * n + 0];
        const float g1 = (float)goals[2 * n + 1];
        const float y_min = fminf(s0, g0), y_max = fmaxf(s0, g0);
        const float x_min = fminf(s1, g1), x_max = fmaxf(s1, g1);
        const float bin_h = (y_max - y_min) * 0.125f;
        const float bin_w = (x_max - x_min) * 0.125f;
        const int   gh = (int)ceilf(bin_h);
        const int   gw = (int)ceilf(bin_w);

        const float start = axis ? (x_min - 0.5f) : (y_min - 0.5f);
        const float bin   = axis ? bin_w : bin_h;
        const int   grid  = axis ? gw : gh;          // <= 4
        const float gsafe = (float)(grid > 1 ? grid : 1);

        float* __restrict__ rec = &s_rec[axis][ph][0];
        #pragma unroll
        for (int k = 0; k < 6; ++k) rec[k] = 0.0f;

        int base = 0, last = -1;
        for (int i = 0; i < grid; ++i) {
            const float pos = start + (float)ph * bin + ((float)i + 0.5f) * (bin / gsafe);
            const float vf  = (pos >= -1.0f && pos <= 32.0f) ? 1.0f : 0.0f;
            const float p   = fminf(fmaxf(pos, 0.0f), 31.0f);
            const int   lo  = (int)floorf(p);
            const int   hi  = min(lo + 1, 31);
            const float l   = p - (float)lo;
            if (i == 0) base = lo;
            rec[lo - base] += (1.0f - l) * vf;   // pos monotone -> lo>=base; span<=4
            rec[hi - base] += l * vf;            // LDS runtime index: native, no scratch
            last = hi;
        }
        rec[6] = (float)base;
        rec[7] = (float)((grid > 0) ? (last - base + 1) : 0);
        if (tid == 0) {
            s_meta[0] = 1.0f / fmaxf((float)(gh * gw), 1.0f);
            s_meta[1] = (float)(((s0 > g0) ? 2 : 0) + ((s1 > g1) ? 1 : 0));
            s_meta[2] = (float)batch_idxs[n];
        }
    }
    __syncthreads();

    // ================= Stage A: y-reduction =================
    const int py = tid >> 5;          // wave-uniform pairs
    const int cp = (tid >> 3) & 3;
    const int xq = tid & 7;
    const float4 ya = *reinterpret_cast<const float4*>(&s_rec[0][py][0]);
    const float4 yb = *reinterpret_cast<const float4*>(&s_rec[0][py][4]);
    const float inv_count = s_meta[0];
    const int   fcode     = (int)s_meta[1];
    const int   b         = (int)s_meta[2];
    {
        const int rb = (int)yb.z;
        const int rc = (int)yb.w;
        const float wy[5] = {ya.x, ya.y, ya.z, ya.w, yb.x};

        const float* __restrict__ fb =
            feats + ((size_t)b * C + (size_t)(cg * CCHUNK + cp * 4)) * 1024 + xq * 4;

        float4 a0 = {0.f,0.f,0.f,0.f}, a1 = {0.f,0.f,0.f,0.f};
        float4 a2 = {0.f,0.f,0.f,0.f}, a3 = {0.f,0.f,0.f,0.f};
        #pragma unroll
        for (int j = 0; j < 5; ++j) {           // rc <= 5; static wy index
            if (j < rc) {
                const float w  = wy[j];
                const int   ro = (rb + j) * 32;
                const float4 r0 = *reinterpret_cast<const float4*>(fb + ro);
                const float4 r1 = *reinterpret_cast<const float4*>(fb + 1024 + ro);
                const float4 r2 = *reinterpret_cast<const float4*>(fb + 2048 + ro);
                const float4 r3 = *reinterpret_cast<const float4*>(fb + 3072 + ro);
                a0.x = fmaf(w, r0.x, a0.x); a0.y = fmaf(w, r0.y, a0.y);
                a0.z = fmaf(w, r0.z, a0.z); a0.w = fmaf(w, r0.w, a0.w);
                a1.x = fmaf(w, r1.x, a1.x); a1.y = fmaf(w, r1.y, a1.y);
                a1.z = fmaf(w, r1.z, a1.z); a1.w = fmaf(w, r1.w, a1.w);
                a2.x = fmaf(w, r2.x, a2.x); a2.y = fmaf(w, r2.y, a2.y);
                a2.z = fmaf(w, r2.z, a2.z); a2.w = fmaf(w, r2.w, a2.w);
                a3.x = fmaf(w, r3.x, a3.x); a3.y = fmaf(w, r3.y, a3.y);
                a3.z = fmaf(w, r3.z, a3.z); a3.w = fmaf(w, r3.w, a3.w);
            }
        }
        const int x0 = xq * 4;
        *reinterpret_cast<float4*>(&s_t[cp * 4 + 0][py][x0]) = a0;
        *reinterpret_cast<float4*>(&s_t[cp * 4 + 1][py][x0]) = a1;
        *reinterpret_cast<float4*>(&s_t[cp * 4 + 2][py][x0]) = a2;
        *reinterpret_cast<float4*>(&s_t[cp * 4 + 3][py][x0]) = a3;
    }

    // ---- stage-B indices + x-record LDS loads issued BEFORE the barrier ----
    const int yx = tid & 63;
    const int y  = yx >> 3;
    const int xo = yx & 7;
    const int c0 = tid >> 6;   // channels {c0, c0+4, c0+8, c0+12}

    // flip-gather source bin (faithful reference-table quirk):
    //  code 0: (y,x) ; codes 1,2 (xor): (y, 7-y) ; code 3: (7-y, x)
    int py2, px;
    if (fcode == 3)      { py2 = H_OUT - 1 - y; px = xo; }
    else if (fcode != 0) { py2 = y;             px = W_OUT - 1 - y; }
    else                 { py2 = y;             px = xo; }

    const float4 xa  = *reinterpret_cast<const float4*>(&s_rec[1][px][0]);
    const float4 xb4 = *reinterpret_cast<const float4*>(&s_rec[1][px][4]);

    __syncthreads();

    // ================= Stage B: x-reduction + flip + write =================
    const int   xbi = (int)xb4.z;
    const int   xc  = (int)xb4.w;
    const float wx[5] = {xa.x, xa.y, xa.z, xa.w, xb4.x};

    float b0 = 0.f, b1 = 0.f, b2 = 0.f, b3 = 0.f;
    #pragma unroll
    for (int j = 0; j < 5; ++j) {               // xc <= 5; static wx index
        if (j < xc) {
            const float w = wx[j];
            b0 = fmaf(w, s_t[c0     ][py2][xbi + j], b0);
            b1 = fmaf(w, s_t[c0 +  4][py2][xbi + j], b1);
            b2 = fmaf(w, s_t[c0 +  8][py2][xbi + j], b2);
            b3 = fmaf(w, s_t[c0 + 12][py2][xbi + j], b3);
        }
    }

    float* __restrict__ ob =
        out + ((size_t)n * C + (size_t)cg * CCHUNK) * (H_OUT * W_OUT);
    ob[tid      ] = b0 * inv_count;
    ob[tid + 256] = b1 * inv_count;
    ob[tid + 512] = b2 * inv_count;
    ob[tid + 768] = b3 * inv_count;
}

extern "C" void kernel_launch(void* const* d_in, const int* in_sizes, int n_in,
                              void* d_out, int out_size, void* d_ws, size_t ws_size,
                              hipStream_t stream) {
    const float* feats      = (const float*)d_in[0];
    const int*   batch_idxs = (const int*)d_in[1];
    const int*   starts     = (const int*)d_in[2];
    const int*   goals      = (const int*)d_in[3];
    float*       out        = (float*)d_out;

    const int N  = in_sizes[1];                       // 1024
    const int C  = out_size / (N * H_OUT * W_OUT);    // 64
    const int CG = C / CCHUNK;                        // 4

    roi_fused<<<N * CG, 256, 0, stream>>>(feats, batch_idxs, starts, goals,
                                          out, C, CG);
}

// Round 12
// 72.394 us; speedup vs baseline: 1.1563x; 1.0119x over previous
//
#include <hip/hip_runtime.h>

#define H_OUT 8
#define W_OUT 8
#define CCHUNK 16    // channels per block

// Per-thread collapsed bin record via hat-function weights (no LDS, no scatter):
//   row weight w[k] = sum_i m_i * max(0, 1 - |p_i - (base+k)|)
// identical to the reference's (1-l)/l bilinear scatter incl. clamp edge cases.
__device__ __forceinline__ void build_rec(
    float start_ph, float bin, int grid,
    float (&wv)[5], int& base, int& cnt)
{
    const float rg  = (grid <= 1) ? 1.0f
                    : (grid == 2 ? 0.5f : (grid == 3 ? (1.0f / 3.0f) : 0.25f));
    const float step = bin * rg;
    float p_[4], m_[4];
    int   lo_[4];
    #pragma unroll
    for (int i = 0; i < 4; ++i) {
        const float pos = fmaf((float)i + 0.5f, step, start_ph);
        const bool  ok  = (i < grid) && (pos >= -1.0f) && (pos <= 32.0f);
        m_[i] = ok ? 1.0f : 0.0f;
        const float p = fminf(fmaxf(pos, 0.0f), 31.0f);
        p_[i]  = p;
        lo_[i] = (int)p;              // p >= 0 -> trunc == floor
    }
    base = lo_[0];
    const float bf = (float)base;
    #pragma unroll
    for (int k = 0; k < 5; ++k) {     // static k -> register indexing
        float w = 0.0f;
        #pragma unroll
        for (int i = 0; i < 4; ++i) {
            const float t = fmaxf(0.0f, 1.0f - fabsf(p_[i] - (bf + (float)k)));
            w = fmaf(t, m_[i], w);
        }
        wv[k] = w;
    }
    int lolast = lo_[0];
    #pragma unroll
    for (int i = 1; i < 4; ++i) lolast = (i < grid) ? lo_[i] : lolast;
    cnt = (grid > 0) ? (min(lolast + 1, 31) - base + 1) : 0;
}

// Fused separable ROI-align + flip, zero serial sections, ONE barrier.
//  Stage A (tid = py*32+cp*8+xq): per-thread y-record; float4 feats rows; -> s_t
//  Stage B: per-thread x-record built BEFORE the barrier; x-reduce + flip + write.
__global__ __launch_bounds__(256) void roi_fused(
    const float* __restrict__ feats,        // [B,C,32,32]
    const int*   __restrict__ batch_idxs,   // [N]
    const int*   __restrict__ starts,       // [N,2]
    const int*   __restrict__ goals,        // [N,2]
    float*       __restrict__ out,          // [N,C,8,8]
    int C, int CG)
{
    const int bx  = blockIdx.x;
    const int n   = bx / CG;
    const int cg  = bx - n * CG;
    const int tid = threadIdx.x;

    __shared__ float s_t[CCHUNK][H_OUT][36];  // pitch 36: 16B-aligned, bank spread

    // ---- entry loads (issued immediately; everything below is VALU) ----
    const int2 sv = *reinterpret_cast<const int2*>(starts + 2 * n);
    const int2 gv = *reinterpret_cast<const int2*>(goals  + 2 * n);
    const int  b  = batch_idxs[n];

    const float s0 = (float)sv.x, s1 = (float)sv.y;
    const float g0 = (float)gv.x, g1 = (float)gv.y;
    const float y_min = fminf(s0, g0), y_max = fmaxf(s0, g0);
    const float x_min = fminf(s1, g1), x_max = fmaxf(s1, g1);
    const float bin_h = (y_max - y_min) * 0.125f;
    const float bin_w = (x_max - x_min) * 0.125f;
    const int   gh = (int)ceilf(bin_h);
    const int   gw = (int)ceilf(bin_w);
    const float inv_count = 1.0f / fmaxf((float)(gh * gw), 1.0f);
    const int   fcode = ((sv.x > gv.x) ? 2 : 0) + ((sv.y > gv.y) ? 1 : 0);

    // ================= Stage A: y-reduction =================
    const int py = tid >> 5;          // wave spans 2 py bins
    const int cp = (tid >> 3) & 3;
    const int xq = tid & 7;
    {
        float wy[5]; int rb, rc;
        build_rec((y_min - 0.5f) + (float)py * bin_h, bin_h, gh, wy, rb, rc);

        const float* __restrict__ fb =
            feats + ((size_t)b * C + (size_t)(cg * CCHUNK + cp * 4)) * 1024 + xq * 4;

        float4 a0 = {0.f,0.f,0.f,0.f}, a1 = {0.f,0.f,0.f,0.f};
        float4 a2 = {0.f,0.f,0.f,0.f}, a3 = {0.f,0.f,0.f,0.f};
        #pragma unroll
        for (int j = 0; j < 5; ++j) {           // rc <= 5; static wy index
            if (j < rc) {
                const float w  = wy[j];
                const int   ro = (rb + j) * 32;
                const float4 r0 = *reinterpret_cast<const float4*>(fb + ro);
                const float4 r1 = *reinterpret_cast<const float4*>(fb + 1024 + ro);
                const float4 r2 = *reinterpret_cast<const float4*>(fb + 2048 + ro);
                const float4 r3 = *reinterpret_cast<const float4*>(fb + 3072 + ro);
                a0.x = fmaf(w, r0.x, a0.x); a0.y = fmaf(w, r0.y, a0.y);
                a0.z = fmaf(w, r0.z, a0.z); a0.w = fmaf(w, r0.w, a0.w);
                a1.x = fmaf(w, r1.x, a1.x); a1.y = fmaf(w, r1.y, a1.y);
                a1.z = fmaf(w, r1.z, a1.z); a1.w = fmaf(w, r1.w, a1.w);
                a2.x = fmaf(w, r2.x, a2.x); a2.y = fmaf(w, r2.y, a2.y);
                a2.z = fmaf(w, r2.z, a2.z); a2.w = fmaf(w, r2.w, a2.w);
                a3.x = fmaf(w, r3.x, a3.x); a3.y = fmaf(w, r3.y, a3.y);
                a3.z = fmaf(w, r3.z, a3.z); a3.w = fmaf(w, r3.w, a3.w);
            }
        }
        const int x0 = xq * 4;
        *reinterpret_cast<float4*>(&s_t[cp * 4 + 0][py][x0]) = a0;
        *reinterpret_cast<float4*>(&s_t[cp * 4 + 1][py][x0]) = a1;
        *reinterpret_cast<float4*>(&s_t[cp * 4 + 2][py][x0]) = a2;
        *reinterpret_cast<float4*>(&s_t[cp * 4 + 3][py][x0]) = a3;
    }

    // ---- stage-B mapping + per-thread x-record, all BEFORE the barrier ----
    const int yx = tid & 63;
    const int y  = yx >> 3;
    const int xo = yx & 7;
    const int c0 = tid >> 6;   // channels {c0, c0+4, c0+8, c0+12}

    // flip-gather source bin (faithful reference-table quirk):
    //  code 0: (y,x) ; codes 1,2 (xor): (y, 7-y) ; code 3: (7-y, x)
    int py2, px;
    if (fcode == 3)      { py2 = H_OUT - 1 - y; px = xo; }
    else if (fcode != 0) { py2 = y;             px = W_OUT - 1 - y; }
    else                 { py2 = y;             px = xo; }

    float wx[5]; int xbi, xc;
    build_rec((x_min - 0.5f) + (float)px * bin_w, bin_w, gw, wx, xbi, xc);

    __syncthreads();

    // ================= Stage B: x-reduction + flip + write =================
    float b0 = 0.f, b1 = 0.f, b2 = 0.f, b3 = 0.f;
    #pragma unroll
    for (int j = 0; j < 5; ++j) {               // xc <= 5; static wx index
        if (j < xc) {
            const float w = wx[j];
            b0 = fmaf(w, s_t[c0     ][py2][xbi + j], b0);
            b1 = fmaf(w, s_t[c0 +  4][py2][xbi + j], b1);
            b2 = fmaf(w, s_t[c0 +  8][py2][xbi + j], b2);
            b3 = fmaf(w, s_t[c0 + 12][py2][xbi + j], b3);
        }
    }

    float* __restrict__ ob =
        out + ((size_t)n * C + (size_t)cg * CCHUNK) * (H_OUT * W_OUT);
    ob[tid      ] = b0 * inv_count;
    ob[tid + 256] = b1 * inv_count;
    ob[tid + 512] = b2 * inv_count;
    ob[tid + 768] = b3 * inv_count;
}

extern "C" void kernel_launch(void* const* d_in, const int* in_sizes, int n_in,
                              void* d_out, int out_size, void* d_ws, size_t ws_size,
                              hipStream_t stream) {
    const float* feats      = (const float*)d_in[0];
    const int*   batch_idxs = (const int*)d_in[1];
    const int*   starts     = (const int*)d_in[2];
    const int*   goals      = (const int*)d_in[3];
    float*       out        = (float*)d_out;

    const int N  = in_sizes[1];                       // 1024
    const int C  = out_size / (N * H_OUT * W_OUT);    // 64
    const int CG = C / CCHUNK;                        // 4

    roi_fused<<<N * CG, 256, 0, stream>>>(feats, batch_idxs, starts, goals,
                                          out, C, CG);
}

// Round 13
// 72.246 us; speedup vs baseline: 1.1586x; 1.0021x over previous
//
#include <hip/hip_runtime.h>

#define H_OUT 8
#define W_OUT 8
#define CCHUNK 16    // channels per block

// Per-thread collapsed bin record via hat-function weights (no LDS, no scatter):
//   row weight w[k] = sum_i m_i * max(0, 1 - |p_i - (base+k)|)
// identical to the reference's (1-l)/l bilinear scatter incl. clamp edge cases.
__device__ __forceinline__ void build_rec(
    float start_ph, float bin, int grid,
    float (&wv)[5], int& base, int& cnt)
{
    const float rg  = (grid <= 1) ? 1.0f
                    : (grid == 2 ? 0.5f : (grid == 3 ? (1.0f / 3.0f) : 0.25f));
    const float step = bin * rg;
    float p_[4], m_[4];
    int   lo_[4];
    #pragma unroll
    for (int i = 0; i < 4; ++i) {
        const float pos = fmaf((float)i + 0.5f, step, start_ph);
        const bool  ok  = (i < grid) && (pos >= -1.0f) && (pos <= 32.0f);
        m_[i] = ok ? 1.0f : 0.0f;
        const float p = fminf(fmaxf(pos, 0.0f), 31.0f);
        p_[i]  = p;
        lo_[i] = (int)p;              // p >= 0 -> trunc == floor
    }
    base = lo_[0];
    const float bf = (float)base;
    #pragma unroll
    for (int k = 0; k < 5; ++k) {     // static k -> register indexing
        float w = 0.0f;
        #pragma unroll
        for (int i = 0; i < 4; ++i) {
            const float t = fmaxf(0.0f, 1.0f - fabsf(p_[i] - (bf + (float)k)));
            w = fmaf(t, m_[i], w);
        }
        wv[k] = w;
    }
    int lolast = lo_[0];
    #pragma unroll
    for (int i = 1; i < 4; ++i) lolast = (i < grid) ? lo_[i] : lolast;
    cnt = (grid > 0) ? (min(lolast + 1, 31) - base + 1) : 0;
}

// Fused separable ROI-align + flip, zero serial sections, ONE barrier.
//  Stage A (tid = py*32+cp*8+xq): per-thread y-record; float4 feats rows; -> s_t
//  Stage B: per-thread x-record built BEFORE the barrier; x-reduce + flip + write.
//  Output stores are nontemporal: out is write-once, never re-read -> keep L2
//  capacity for feats (per-XCD L2 is 4 MiB vs 8 MB feats working set).
__global__ __launch_bounds__(256) void roi_fused(
    const float* __restrict__ feats,        // [B,C,32,32]
    const int*   __restrict__ batch_idxs,   // [N]
    const int*   __restrict__ starts,       // [N,2]
    const int*   __restrict__ goals,        // [N,2]
    float*       __restrict__ out,          // [N,C,8,8]
    int C, int CG)
{
    const int bx  = blockIdx.x;
    const int n   = bx / CG;
    const int cg  = bx - n * CG;
    const int tid = threadIdx.x;

    __shared__ float s_t[CCHUNK][H_OUT][36];  // pitch 36: 16B-aligned, bank spread

    // ---- entry loads (issued immediately; everything below is VALU) ----
    const int2 sv = *reinterpret_cast<const int2*>(starts + 2 * n);
    const int2 gv = *reinterpret_cast<const int2*>(goals  + 2 * n);
    const int  b  = batch_idxs[n];

    const float s0 = (float)sv.x, s1 = (float)sv.y;
    const float g0 = (float)gv.x, g1 = (float)gv.y;
    const float y_min = fminf(s0, g0), y_max = fmaxf(s0, g0);
    const float x_min = fminf(s1, g1), x_max = fmaxf(s1, g1);
    const float bin_h = (y_max - y_min) * 0.125f;
    const float bin_w = (x_max - x_min) * 0.125f;
    const int   gh = (int)ceilf(bin_h);
    const int   gw = (int)ceilf(bin_w);
    const float inv_count = 1.0f / fmaxf((float)(gh * gw), 1.0f);
    const int   fcode = ((sv.x > gv.x) ? 2 : 0) + ((sv.y > gv.y) ? 1 : 0);

    // ================= Stage A: y-reduction =================
    const int py = tid >> 5;          // wave spans 2 py bins
    const int cp = (tid >> 3) & 3;
    const int xq = tid & 7;
    {
        float wy[5]; int rb, rc;
        build_rec((y_min - 0.5f) + (float)py * bin_h, bin_h, gh, wy, rb, rc);

        const float* __restrict__ fb =
            feats + ((size_t)b * C + (size_t)(cg * CCHUNK + cp * 4)) * 1024 + xq * 4;

        float4 a0 = {0.f,0.f,0.f,0.f}, a1 = {0.f,0.f,0.f,0.f};
        float4 a2 = {0.f,0.f,0.f,0.f}, a3 = {0.f,0.f,0.f,0.f};
        #pragma unroll
        for (int j = 0; j < 5; ++j) {           // rc <= 5; static wy index
            if (j < rc) {
                const float w  = wy[j];
                const int   ro = (rb + j) * 32;
                const float4 r0 = *reinterpret_cast<const float4*>(fb + ro);
                const float4 r1 = *reinterpret_cast<const float4*>(fb + 1024 + ro);
                const float4 r2 = *reinterpret_cast<const float4*>(fb + 2048 + ro);
                const float4 r3 = *reinterpret_cast<const float4*>(fb + 3072 + ro);
                a0.x = fmaf(w, r0.x, a0.x); a0.y = fmaf(w, r0.y, a0.y);
                a0.z = fmaf(w, r0.z, a0.z); a0.w = fmaf(w, r0.w, a0.w);
                a1.x = fmaf(w, r1.x, a1.x); a1.y = fmaf(w, r1.y, a1.y);
                a1.z = fmaf(w, r1.z, a1.z); a1.w = fmaf(w, r1.w, a1.w);
                a2.x = fmaf(w, r2.x, a2.x); a2.y = fmaf(w, r2.y, a2.y);
                a2.z = fmaf(w, r2.z, a2.z); a2.w = fmaf(w, r2.w, a2.w);
                a3.x = fmaf(w, r3.x, a3.x); a3.y = fmaf(w, r3.y, a3.y);
                a3.z = fmaf(w, r3.z, a3.z); a3.w = fmaf(w, r3.w, a3.w);
            }
        }
        const int x0 = xq * 4;
        *reinterpret_cast<float4*>(&s_t[cp * 4 + 0][py][x0]) = a0;
        *reinterpret_cast<float4*>(&s_t[cp * 4 + 1][py][x0]) = a1;
        *reinterpret_cast<float4*>(&s_t[cp * 4 + 2][py][x0]) = a2;
        *reinterpret_cast<float4*>(&s_t[cp * 4 + 3][py][x0]) = a3;
    }

    // ---- stage-B mapping + per-thread x-record, all BEFORE the barrier ----
    const int yx = tid & 63;
    const int y  = yx >> 3;
    const int xo = yx & 7;
    const int c0 = tid >> 6;   // channels {c0, c0+4, c0+8, c0+12}

    // flip-gather source bin (faithful reference-table quirk):
    //  code 0: (y,x) ; codes 1,2 (xor): (y, 7-y) ; code 3: (7-y, x)
    int py2, px;
    if (fcode == 3)      { py2 = H_OUT - 1 - y; px = xo; }
    else if (fcode != 0) { py2 = y;             px = W_OUT - 1 - y; }
    else                 { py2 = y;             px = xo; }

    float wx[5]; int xbi, xc;
    build_rec((x_min - 0.5f) + (float)px * bin_w, bin_w, gw, wx, xbi, xc);

    __syncthreads();

    // ================= Stage B: x-reduction + flip + write =================
    float b0 = 0.f, b1 = 0.f, b2 = 0.f, b3 = 0.f;
    #pragma unroll
    for (int j = 0; j < 5; ++j) {               // xc <= 5; static wx index
        if (j < xc) {
            const float w = wx[j];
            b0 = fmaf(w, s_t[c0     ][py2][xbi + j], b0);
            b1 = fmaf(w, s_t[c0 +  4][py2][xbi + j], b1);
            b2 = fmaf(w, s_t[c0 +  8][py2][xbi + j], b2);
            b3 = fmaf(w, s_t[c0 + 12][py2][xbi + j], b3);
        }
    }

    float* __restrict__ ob =
        out + ((size_t)n * C + (size_t)cg * CCHUNK) * (H_OUT * W_OUT);
    __builtin_nontemporal_store(b0 * inv_count, ob + tid);
    __builtin_nontemporal_store(b1 * inv_count, ob + tid + 256);
    __builtin_nontemporal_store(b2 * inv_count, ob + tid + 512);
    __builtin_nontemporal_store(b3 * inv_count, ob + tid + 768);
}

extern "C" void kernel_launch(void* const* d_in, const int* in_sizes, int n_in,
                              void* d_out, int out_size, void* d_ws, size_t ws_size,
                              hipStream_t stream) {
    const float* feats      = (const float*)d_in[0];
    const int*   batch_idxs = (const int*)d_in[1];
    const int*   starts     = (const int*)d_in[2];
    const int*   goals      = (const int*)d_in[3];
    float*       out        = (float*)d_out;

    const int N  = in_sizes[1];                       // 1024
    const int C  = out_size / (N * H_OUT * W_OUT);    // 64
    const int CG = C / CCHUNK;                        // 4

    roi_fused<<<N * CG, 256, 0, stream>>>(feats, batch_idxs, starts, goals,
                                          out, C, CG);
}